// Round 12
// baseline (255.517 us; speedup 1.0000x reference)
//
#include <hip/hip_runtime.h>
#include <cstdint>

typedef __bf16 bf16x8 __attribute__((ext_vector_type(8)));
typedef float f32x4 __attribute__((ext_vector_type(4)));
typedef float f32x16 __attribute__((ext_vector_type(16)));
typedef unsigned short u16;

#define MFMA16(a, b, c) __builtin_amdgcn_mfma_f32_16x16x32_bf16((a), (b), (c), 0, 0, 0)
#define MFMA32(a, b, c) __builtin_amdgcn_mfma_f32_32x32x16_bf16((a), (b), (c), 0, 0, 0)

// async global->LDS, 16B per lane; LDS dest = wave-uniform base + lane*16
#define GLLDS(gp, lp) __builtin_amdgcn_global_load_lds( \
    (const __attribute__((address_space(1))) uint32_t*)(gp), \
    (__attribute__((address_space(3))) uint32_t*)(lp), 16, 0, 0)

__device__ __forceinline__ u16 f2bf(float f) {
    union { float f; uint32_t u; } v; v.f = f;
    uint32_t u = v.u;
    u += 0x7FFFu + ((u >> 16) & 1u);   // RNE
    return (u16)(u >> 16);
}
__device__ __forceinline__ float bf2f(u16 h) {
    union { uint32_t u; float f; } v; v.u = ((uint32_t)h) << 16;
    return v.f;
}

// ---------------------------------------------------------------- fused preprocessing
// One launch: all 7 weight transposes (fp32 [R][C] -> bf16 [C][R]) + LayerNorm.
__global__ __launch_bounds__(256) void prep_kernel(
    const float* __restrict__ wq, const float* __restrict__ wk,
    const float* __restrict__ wv, const float* __restrict__ wo,
    const float* __restrict__ wg, const float* __restrict__ wu,
    const float* __restrict__ wd,
    const float* __restrict__ x, const float* __restrict__ ln_w,
    const float* __restrict__ ln_b,
    u16* __restrict__ QKVT, u16* __restrict__ WOT, u16* __restrict__ WGT,
    u16* __restrict__ WUT, u16* __restrict__ WDT, u16* __restrict__ NORMED) {
    const int bid = blockIdx.x;
    const int tid = threadIdx.x;

    if (bid < 14848) {      // ---- transpose segments ----
        const float* in; u16* out; int R, C, gx; int t = bid;
        if (t < 1024)              { in = wq; out = QKVT;                         R = 1024; C = 1024; gx = 32; }
        else if ((t -= 1024) < 256)  { in = wk; out = QKVT + (size_t)1024 * 1024; R = 1024; C = 256;  gx = 8; }
        else if ((t -= 256) < 256)   { in = wv; out = QKVT + (size_t)1280 * 1024; R = 1024; C = 256;  gx = 8; }
        else if ((t -= 256) < 1024)  { in = wo; out = WOT;                        R = 1024; C = 1024; gx = 32; }
        else if ((t -= 1024) < 4096) { in = wg; out = WGT;                        R = 1024; C = 4096; gx = 128; }
        else if ((t -= 4096) < 4096) { in = wu; out = WUT;                        R = 1024; C = 4096; gx = 128; }
        else          { t -= 4096;     in = wd; out = WDT;                        R = 4096; C = 1024; gx = 32; }
        const int bx = t % gx, by = t / gx;
        __shared__ float tile[32][33];
        const int c0 = bx * 32, r0 = by * 32;
        const int tx = tid & 31, ty = tid >> 5;
#pragma unroll
        for (int i = ty; i < 32; i += 8)
            tile[i][tx] = in[(size_t)(r0 + i) * C + c0 + tx];
        __syncthreads();
#pragma unroll
        for (int i = ty; i < 32; i += 8)
            out[(size_t)(c0 + i) * R + r0 + tx] = f2bf(tile[tx][i]);
    } else {                // ---- LayerNorm segment ----
        const int row = bid - 14848;
        float4 v = ((const float4*)(x + (size_t)row * 1024))[tid];
        float s = v.x + v.y + v.z + v.w;
        float s2 = v.x * v.x + v.y * v.y + v.z * v.z + v.w * v.w;
#pragma unroll
        for (int off = 1; off < 64; off <<= 1) {
            s += __shfl_xor(s, off);
            s2 += __shfl_xor(s2, off);
        }
        __shared__ float rs[4], rs2[4];
        const int wv4i = tid >> 6;
        if ((tid & 63) == 0) { rs[wv4i] = s; rs2[wv4i] = s2; }
        __syncthreads();
        s = rs[0] + rs[1] + rs[2] + rs[3];
        s2 = rs2[0] + rs2[1] + rs2[2] + rs2[3];
        float mu = s * (1.0f / 1024.0f);
        float var = s2 * (1.0f / 1024.0f) - mu * mu;
        float inv = rsqrtf(var + 1e-5f);
        float4 wv4 = ((const float4*)ln_w)[tid];
        float4 bv4 = ((const float4*)ln_b)[tid];
        ushort4 o;
        o.x = f2bf((v.x - mu) * inv * wv4.x + bv4.x);
        o.y = f2bf((v.y - mu) * inv * wv4.y + bv4.y);
        o.z = f2bf((v.z - mu) * inv * wv4.z + bv4.z);
        o.w = f2bf((v.w - mu) * inv * wv4.w + bv4.w);
        *(ushort4*)(NORMED + (size_t)row * 1024 + tid * 4) = o;
    }
}

// bf16 transpose of V section of qkv: in [B*2048][1536] cols 1280.. -> vT [b][kh][64][2048]
__global__ __launch_bounds__(256) void transpose_v(const u16* __restrict__ in, u16* __restrict__ out,
                                                   int in_stride) {
    __shared__ u16 tile[32][33];
    int b = blockIdx.z;
    int c0 = blockIdx.x * 32, s0 = blockIdx.y * 32;
    int tx = threadIdx.x & 31, ty = threadIdx.x >> 5;
#pragma unroll
    for (int i = ty; i < 32; i += 8)
        tile[i][tx] = in[(size_t)(b * 2048 + s0 + i) * in_stride + c0 + tx];
    __syncthreads();
#pragma unroll
    for (int i = ty; i < 32; i += 8)
        out[(size_t)b * 256 * 2048 + (size_t)(c0 + i) * 2048 + s0 + tx] = tile[tx][i];
}

// ---------------------------------------------------------------- merged NORMED-consumer GEMMs
// Blocks 0..2047:   Hb  = silu(NORMED @ WGT^T) * (NORMED @ WUT^T)   (gateup, 32x64 tiles)
// Blocks 2048..2815: QKV = NORMED @ QKVT^T                          (qkv,    32x24 tiles)
// Both read only NORMED -> independent outputs; one dispatch lets QKV's 768 blocks fill
// CU slots during gateup's ramp/tail and removes a launch boundary.
// BM=128 x BN=64, BK=64, XOR-swizzled LDS (0 bank conflicts, round-7 verified).
__global__ __launch_bounds__(256) void gemm_nproj(const u16* __restrict__ A,
                                                  const u16* __restrict__ Bg,
                                                  const u16* __restrict__ Bu,
                                                  const u16* __restrict__ Bqkv,
                                                  u16* __restrict__ H,
                                                  u16* __restrict__ QKV) {
    __shared__ __align__(16) u16 As[128 * 64];
    __shared__ __align__(16) u16 Bs[64 * 64];
    __shared__ __align__(16) u16 Bs2[64 * 64];
    const int tid = threadIdx.x, lane = tid & 63, wv = tid >> 6;
    const int wr = (wv >> 1) * 64, wc = (wv & 1) * 32;
    const int fr = lane & 15, fg = lane >> 4;
    const int lr8 = lane >> 3;
    const int lc8s = ((lane & 7) ^ lr8) * 8;   // pre-swizzled source colblock
    const int f7 = fr & 7;
    const int K = 1024;

    if (blockIdx.x < 2048) {
        // ---------------- gateup branch ----------------
        const int row0 = (blockIdx.x & 31) * 128, col0 = (blockIdx.x >> 5) * 64;

        f32x4 ag[4][2], au[4][2];
#pragma unroll
        for (int i = 0; i < 4; ++i)
#pragma unroll
            for (int j = 0; j < 2; ++j) {
                ag[i][j] = (f32x4){0.f, 0.f, 0.f, 0.f};
                au[i][j] = (f32x4){0.f, 0.f, 0.f, 0.f};
            }

        const u16* ga = A + (size_t)(row0 + 32 * wv + lr8) * K + lc8s;
        const u16* gg = Bg + (size_t)(col0 + 16 * wv + lr8) * K + lc8s;
        const u16* gu = Bu + (size_t)(col0 + 16 * wv + lr8) * K + lc8s;
        u16* la = As + wv * 2048;
        u16* lg = Bs + wv * 1024;
        u16* lu = Bs2 + wv * 1024;

        for (int k0 = 0; k0 < K; k0 += 64) {
            __syncthreads();
            GLLDS(ga + k0, la);
            GLLDS(ga + (size_t)8 * K + k0, la + 512);
            GLLDS(ga + (size_t)16 * K + k0, la + 1024);
            GLLDS(ga + (size_t)24 * K + k0, la + 1536);
            GLLDS(gg + k0, lg);
            GLLDS(gg + (size_t)8 * K + k0, lg + 512);
            GLLDS(gu + k0, lu);
            GLLDS(gu + (size_t)8 * K + k0, lu + 512);
            __syncthreads();
#pragma unroll
            for (int kk = 0; kk < 2; ++kk) {
                bf16x8 af[4], bg[2], bu[2];
#pragma unroll
                for (int i = 0; i < 4; ++i)
                    af[i] = *(const bf16x8*)(As + (wr + i * 16 + fr) * 64 + (((kk * 4 + fg) ^ f7) * 8));
#pragma unroll
                for (int j = 0; j < 2; ++j) {
                    bg[j] = *(const bf16x8*)(Bs + (wc + j * 16 + fr) * 64 + (((kk * 4 + fg) ^ f7) * 8));
                    bu[j] = *(const bf16x8*)(Bs2 + (wc + j * 16 + fr) * 64 + (((kk * 4 + fg) ^ f7) * 8));
                }
#pragma unroll
                for (int i = 0; i < 4; ++i)
#pragma unroll
                    for (int j = 0; j < 2; ++j) {
                        ag[i][j] = MFMA16(af[i], bg[j], ag[i][j]);
                        au[i][j] = MFMA16(af[i], bu[j], au[i][j]);
                    }
            }
        }

#pragma unroll
        for (int i = 0; i < 4; ++i)
#pragma unroll
            for (int j = 0; j < 2; ++j)
#pragma unroll
                for (int r = 0; r < 4; ++r) {
                    int row = row0 + wr + i * 16 + fg * 4 + r;
                    int col = col0 + wc + j * 16 + fr;
                    float g = ag[i][j][r];
                    float sg = g / (1.0f + __expf(-g));
                    H[(size_t)row * 4096 + col] = f2bf(sg * au[i][j][r]);
                }
    } else {
        // ---------------- QKV branch ----------------
        const int t = blockIdx.x - 2048;
        const int row0 = (t & 31) * 128, col0 = (t >> 5) * 64;

        f32x4 acc[4][2];
#pragma unroll
        for (int i = 0; i < 4; ++i)
#pragma unroll
            for (int j = 0; j < 2; ++j) acc[i][j] = (f32x4){0.f, 0.f, 0.f, 0.f};

        const u16* ga = A + (size_t)(row0 + 32 * wv + lr8) * K + lc8s;
        const u16* gb = Bqkv + (size_t)(col0 + 16 * wv + lr8) * K + lc8s;
        u16* la = As + wv * 2048;
        u16* lb = Bs + wv * 1024;

        for (int k0 = 0; k0 < K; k0 += 64) {
            __syncthreads();
            GLLDS(ga + k0, la);
            GLLDS(ga + (size_t)8 * K + k0, la + 512);
            GLLDS(ga + (size_t)16 * K + k0, la + 1024);
            GLLDS(ga + (size_t)24 * K + k0, la + 1536);
            GLLDS(gb + k0, lb);
            GLLDS(gb + (size_t)8 * K + k0, lb + 512);
            __syncthreads();
#pragma unroll
            for (int kk = 0; kk < 2; ++kk) {
                bf16x8 af[4], bfr[2];
#pragma unroll
                for (int i = 0; i < 4; ++i)
                    af[i] = *(const bf16x8*)(As + (wr + i * 16 + fr) * 64 + (((kk * 4 + fg) ^ f7) * 8));
#pragma unroll
                for (int j = 0; j < 2; ++j)
                    bfr[j] = *(const bf16x8*)(Bs + (wc + j * 16 + fr) * 64 + (((kk * 4 + fg) ^ f7) * 8));
#pragma unroll
                for (int i = 0; i < 4; ++i)
#pragma unroll
                    for (int j = 0; j < 2; ++j)
                        acc[i][j] = MFMA16(af[i], bfr[j], acc[i][j]);
            }
        }

#pragma unroll
        for (int i = 0; i < 4; ++i)
#pragma unroll
            for (int j = 0; j < 2; ++j)
#pragma unroll
                for (int r = 0; r < 4; ++r) {
                    int row = row0 + wr + i * 16 + fg * 4 + r;
                    int col = col0 + wc + j * 16 + fr;
                    QKV[(size_t)row * 1536 + col] = f2bf(acc[i][j][r]);
                }
    }
}

// ---------------------------------------------------------------- fused output GEMM
// out[4096][1024] = x + ATTN @ WOT^T + Hb @ WDT^T  (concatenated K = 5120)
__global__ __launch_bounds__(256) void gemm_out_fused(const u16* __restrict__ A1,
                                                      const u16* __restrict__ B1t,
                                                      const u16* __restrict__ A2,
                                                      const u16* __restrict__ B2t,
                                                      const float* __restrict__ xres,
                                                      float* __restrict__ C) {
    __shared__ __align__(16) u16 As[128 * 64];
    __shared__ __align__(16) u16 Bs[64 * 64];
    const int tid = threadIdx.x, lane = tid & 63, wv = tid >> 6;
    const int row0 = blockIdx.x * 128, col0 = blockIdx.y * 64;
    const int wr = (wv >> 1) * 64, wc = (wv & 1) * 32;
    const int fr = lane & 15, fg = lane >> 4;
    const int lr8 = lane >> 3;
    const int lc8s = ((lane & 7) ^ lr8) * 8;
    const int f7 = fr & 7;

    f32x4 acc[4][2];
#pragma unroll
    for (int i = 0; i < 4; ++i)
#pragma unroll
        for (int j = 0; j < 2; ++j) acc[i][j] = (f32x4){0.f, 0.f, 0.f, 0.f};

    const int rowA = row0 + 32 * wv + lr8;
    const int rowB = col0 + 16 * wv + lr8;
    u16* la = As + wv * 2048;
    u16* lb = Bs + wv * 1024;

    for (int t = 0; t < 80; ++t) {
        const u16* ga;
        const u16* gb;
        size_t sa, sb;
        if (t < 16) {          // segment 1: ATTN @ WOT (K=1024)
            const int ko = t * 64;
            ga = A1 + (size_t)rowA * 1024 + ko + lc8s; sa = 1024;
            gb = B1t + (size_t)rowB * 1024 + ko + lc8s; sb = 1024;
        } else {               // segment 2: Hb @ WDT (K=4096)
            const int ko = (t - 16) * 64;
            ga = A2 + (size_t)rowA * 4096 + ko + lc8s; sa = 4096;
            gb = B2t + (size_t)rowB * 4096 + ko + lc8s; sb = 4096;
        }
        __syncthreads();
        GLLDS(ga, la);
        GLLDS(ga + 8 * sa, la + 512);
        GLLDS(ga + 16 * sa, la + 1024);
        GLLDS(ga + 24 * sa, la + 1536);
        GLLDS(gb, lb);
        GLLDS(gb + 8 * sb, lb + 512);
        __syncthreads();
#pragma unroll
        for (int kk = 0; kk < 2; ++kk) {
            bf16x8 af[4], bfr[2];
#pragma unroll
            for (int i = 0; i < 4; ++i)
                af[i] = *(const bf16x8*)(As + (wr + i * 16 + fr) * 64 + (((kk * 4 + fg) ^ f7) * 8));
#pragma unroll
            for (int j = 0; j < 2; ++j)
                bfr[j] = *(const bf16x8*)(Bs + (wc + j * 16 + fr) * 64 + (((kk * 4 + fg) ^ f7) * 8));
#pragma unroll
            for (int i = 0; i < 4; ++i)
#pragma unroll
                for (int j = 0; j < 2; ++j)
                    acc[i][j] = MFMA16(af[i], bfr[j], acc[i][j]);
        }
    }

#pragma unroll
    for (int i = 0; i < 4; ++i)
#pragma unroll
        for (int j = 0; j < 2; ++j)
#pragma unroll
            for (int r = 0; r < 4; ++r) {
                int row = row0 + wr + i * 16 + fg * 4 + r;
                int col = col0 + wc + j * 16 + fr;
                size_t off = (size_t)row * 1024 + col;
                C[off] = acc[i][j][r] + xres[off];
            }
}

// ---------------------------------------------------------------- flash attention, 8-warp 32x32
__global__ __launch_bounds__(512) void attn_kernel(const u16* __restrict__ qkv,
                                                   const u16* __restrict__ Vt,
                                                   u16* __restrict__ Ob) {
    __shared__ __align__(16) u16 Ks[2][64 * 64];
    __shared__ __align__(16) u16 Vs[2][64 * 64];
    const int tid = threadIdx.x, lane = tid & 63, w = tid >> 6;
    const int bid = blockIdx.x;
    const int qblk = 7 - (bid & 7);      // longest blocks dispatch first
    const int h = (bid >> 3) & 15;
    const int b = bid >> 7;
    const int kh = h >> 2;
    const int q0 = qblk * 256;
    const int lo = lane & 31, hi = lane >> 5;
    const int qg = q0 + w * 32 + lo;
    const int S = 2048, QS = 1536;

    bf16x8 qf[4];
    {
        const u16* qrow = qkv + (size_t)(b * S + qg) * QS + h * 64 + 8 * hi;
        qf[0] = *(const bf16x8*)(qrow);
        qf[1] = *(const bf16x8*)(qrow + 16);
        qf[2] = *(const bf16x8*)(qrow + 32);
        qf[3] = *(const bf16x8*)(qrow + 48);
    }

    f32x16 o0 = {}, o1 = {};
    float mr = -1e30f, ls = 0.f;
    const int nt = (q0 >> 6) + 4;
    const int wq0 = q0 + w * 32;

    const int sr = w * 8 + (lane >> 3);
    const int scb = ((lane & 7) ^ (sr & 7)) * 8;
    const u16* kg = qkv + (size_t)b * S * QS + 1024 + kh * 64 + scb;
    const u16* vg = Vt + (size_t)(b * 4 + kh) * 64 * 2048 + (size_t)sr * 2048 + scb;
    u16* lk = (u16*)Ks + w * 512;
    u16* lv = (u16*)Vs + w * 512;

#define STAGE(buf, t) { const int kv0s = (t) * 64; \
    GLLDS(kg + (size_t)(kv0s + sr) * QS, lk + (buf) * 4096); \
    GLLDS(vg + kv0s, lv + (buf) * 4096); }

    STAGE(0, 0)
    asm volatile("s_waitcnt vmcnt(0)" ::: "memory");
    __syncthreads();

    const int lrow = lo * 64;
    const int l7 = lo & 7;

    for (int t = 0; t < nt; ++t) {
        const int cur = t & 1;
        if (t + 1 < nt) STAGE(cur ^ 1, t + 1)
        const int kv0 = t * 64;
        if (kv0 <= wq0 + 31) {
            const u16* KB = (const u16*)Ks + cur * 4096;
            const u16* VB = (const u16*)Vs + cur * 4096;
            f32x16 sc0 = {}, sc1 = {};
#pragma unroll
            for (int ds = 0; ds < 4; ++ds) {
                bf16x8 kf0 = *(const bf16x8*)(KB + lrow + (((2 * ds + hi) ^ l7) * 8));
                sc0 = MFMA32(kf0, qf[ds], sc0);
                bf16x8 kf1 = *(const bf16x8*)(KB + 2048 + lrow + (((2 * ds + hi) ^ l7) * 8));
                sc1 = MFMA32(kf1, qf[ds], sc1);
            }

            float xv[32];
            if (kv0 + 63 <= wq0) {
#pragma unroll
                for (int i = 0; i < 16; ++i) {
                    xv[i] = sc0[i] * 0.125f;
                    xv[16 + i] = sc1[i] * 0.125f;
                }
            } else {
#pragma unroll
                for (int i = 0; i < 16; ++i) {
                    int k0g = kv0 + (i & 3) + 8 * (i >> 2) + 4 * hi;
                    xv[i]      = (k0g      <= qg) ? sc0[i] * 0.125f : -1e30f;
                    xv[16 + i] = (k0g + 32 <= qg) ? sc1[i] * 0.125f : -1e30f;
                }
            }
            float m = xv[0];
#pragma unroll
            for (int i = 1; i < 32; ++i) m = fmaxf(m, xv[i]);
            m = fmaxf(m, __shfl_xor(m, 32));
            float nm = fmaxf(mr, m);
            float al = __expf(mr - nm);
            mr = nm;
            float sum = 0.f;
#pragma unroll
            for (int i = 0; i < 32; ++i) {
                float p = __expf(xv[i] - nm);
                xv[i] = p;
                sum += p;
            }
            sum += __shfl_xor(sum, 32);
            ls = ls * al + sum;
#pragma unroll
            for (int i = 0; i < 16; ++i) { o0[i] *= al; o1[i] *= al; }

            bf16x8 pf[4];
#pragma unroll
            for (int g = 0; g < 4; ++g) {
                uint32_t w0, w1, w2, w3;
                asm("v_cvt_pk_bf16_f32 %0, %1, %2" : "=v"(w0) : "v"(xv[g * 8 + 0]), "v"(xv[g * 8 + 1]));
                asm("v_cvt_pk_bf16_f32 %0, %1, %2" : "=v"(w1) : "v"(xv[g * 8 + 2]), "v"(xv[g * 8 + 3]));
                asm("v_cvt_pk_bf16_f32 %0, %1, %2" : "=v"(w2) : "v"(xv[g * 8 + 4]), "v"(xv[g * 8 + 5]));
                asm("v_cvt_pk_bf16_f32 %0, %1, %2" : "=v"(w3) : "v"(xv[g * 8 + 6]), "v"(xv[g * 8 + 7]));
                asm volatile("v_permlane32_swap_b32 %0, %1" : "+v"(w0), "+v"(w2));
                asm volatile("v_permlane32_swap_b32 %0, %1" : "+v"(w1), "+v"(w3));
                union { uint32_t u[4]; bf16x8 v; } pk;
                pk.u[0] = w0; pk.u[1] = w1; pk.u[2] = w2; pk.u[3] = w3;
                pf[g] = pk.v;
            }

#pragma unroll
            for (int ks = 0; ks < 4; ++ks) {
                bf16x8 vf0 = *(const bf16x8*)(VB + lrow + (((2 * ks + hi) ^ l7) * 8));
                o0 = MFMA32(vf0, pf[ks], o0);
                bf16x8 vf1 = *(const bf16x8*)(VB + 2048 + lrow + (((2 * ks + hi) ^ l7) * 8));
                o1 = MFMA32(vf1, pf[ks], o1);
            }
        }
        asm volatile("s_waitcnt vmcnt(0)" ::: "memory");
        __syncthreads();
    }
#undef STAGE

    const float inv = 1.0f / ls;
    u16* orow = Ob + (size_t)(b * S + qg) * 1024 + h * 64;
#pragma unroll
    for (int rg = 0; rg < 4; ++rg) {
        ushort4 w4;
        w4.x = f2bf(o0[rg * 4 + 0] * inv);
        w4.y = f2bf(o0[rg * 4 + 1] * inv);
        w4.z = f2bf(o0[rg * 4 + 2] * inv);
        w4.w = f2bf(o0[rg * 4 + 3] * inv);
        *(ushort4*)(orow + rg * 8 + 4 * hi) = w4;
        w4.x = f2bf(o1[rg * 4 + 0] * inv);
        w4.y = f2bf(o1[rg * 4 + 1] * inv);
        w4.z = f2bf(o1[rg * 4 + 2] * inv);
        w4.w = f2bf(o1[rg * 4 + 3] * inv);
        *(ushort4*)(orow + 32 + rg * 8 + 4 * hi) = w4;
    }
}

// ---------------------------------------------------------------- launch
extern "C" void kernel_launch(void* const* d_in, const int* in_sizes, int n_in,
                              void* d_out, int out_size, void* d_ws, size_t ws_size,
                              hipStream_t stream) {
    const float* x    = (const float*)d_in[0];
    const float* ln_w = (const float*)d_in[1];
    const float* ln_b = (const float*)d_in[2];
    const float* wq   = (const float*)d_in[3];
    const float* wk   = (const float*)d_in[4];
    const float* wv   = (const float*)d_in[5];
    const float* wo   = (const float*)d_in[6];
    const float* wg   = (const float*)d_in[7];
    const float* wu   = (const float*)d_in[8];
    const float* wd   = (const float*)d_in[9];
    float* out = (float*)d_out;

    char* ws = (char*)d_ws;
    u16* QKVT   = (u16*)(ws + 0x0000000);   // [1536][1024] bf16  3MB
    u16* WOT    = (u16*)(ws + 0x0300000);   // [1024][1024] bf16  2MB
    u16* WGT    = (u16*)(ws + 0x0500000);   // [4096][1024] bf16  8MB
    u16* WUT    = (u16*)(ws + 0x0D00000);   // [4096][1024] bf16  8MB
    u16* WDT    = (u16*)(ws + 0x1500000);   // [1024][4096] bf16  8MB
    u16* NORMED = (u16*)(ws + 0x1D00000);   // [4096][1024] bf16  8MB
    u16* QKV    = (u16*)(ws + 0x2500000);   // [4096][1536] bf16 12MB
    u16* VT     = (u16*)(ws + 0x3100000);   // [2][4][64][2048]   2MB
    u16* ATTN   = (u16*)(ws + 0x3300000);   // [4096][1024] bf16  8MB
    u16* Hb     = (u16*)(ws + 0x3B00000);   // [4096][4096] bf16 32MB

    // 1. fused preprocessing: all weight transposes + layernorm (one launch)
    prep_kernel<<<18944, 256, 0, stream>>>(wq, wk, wv, wo, wg, wu, wd,
                                           x, ln_w, ln_b,
                                           QKVT, WOT, WGT, WUT, WDT, NORMED);

    // 2. merged NORMED-consumers: gateup (blocks 0..2047) + QKV proj (2048..2815)
    gemm_nproj<<<2816, 256, 0, stream>>>(NORMED, WGT, WUT, QKVT, Hb, QKV);

    // 3. attention path
    transpose_v<<<dim3(8, 64, 2), 256, 0, stream>>>(QKV + 1280, VT, 1536);
    attn_kernel<<<256, 512, 0, stream>>>(QKV, VT, ATTN);

    // 4. fused output: out = x + ATTN@WO^T + Hb@WD^T  (K=5120 concatenated)
    gemm_out_fused<<<dim3(32, 16), 256, 0, stream>>>(ATTN, WOT, Hb, WDT, x, out);
}

// Round 13
// 252.156 us; speedup vs baseline: 1.0133x; 1.0133x over previous
//
#include <hip/hip_runtime.h>
#include <cstdint>

typedef __bf16 bf16x8 __attribute__((ext_vector_type(8)));
typedef float f32x4 __attribute__((ext_vector_type(4)));
typedef float f32x16 __attribute__((ext_vector_type(16)));
typedef unsigned short u16;

#define MFMA16(a, b, c) __builtin_amdgcn_mfma_f32_16x16x32_bf16((a), (b), (c), 0, 0, 0)
#define MFMA32(a, b, c) __builtin_amdgcn_mfma_f32_32x32x16_bf16((a), (b), (c), 0, 0, 0)

// async global->LDS, 16B per lane; LDS dest = wave-uniform base + lane*16
#define GLLDS(gp, lp) __builtin_amdgcn_global_load_lds( \
    (const __attribute__((address_space(1))) uint32_t*)(gp), \
    (__attribute__((address_space(3))) uint32_t*)(lp), 16, 0, 0)

__device__ __forceinline__ u16 f2bf(float f) {
    union { float f; uint32_t u; } v; v.f = f;
    uint32_t u = v.u;
    u += 0x7FFFu + ((u >> 16) & 1u);   // RNE
    return (u16)(u >> 16);
}
__device__ __forceinline__ float bf2f(u16 h) {
    union { uint32_t u; float f; } v; v.u = ((uint32_t)h) << 16;
    return v.f;
}

// ---------------------------------------------------------------- fused preprocessing
// One launch: all 7 weight transposes (fp32 [R][C] -> bf16 [C][R]) + LayerNorm.
__global__ __launch_bounds__(256) void prep_kernel(
    const float* __restrict__ wq, const float* __restrict__ wk,
    const float* __restrict__ wv, const float* __restrict__ wo,
    const float* __restrict__ wg, const float* __restrict__ wu,
    const float* __restrict__ wd,
    const float* __restrict__ x, const float* __restrict__ ln_w,
    const float* __restrict__ ln_b,
    u16* __restrict__ QKVT, u16* __restrict__ WOT, u16* __restrict__ WGT,
    u16* __restrict__ WUT, u16* __restrict__ WDT, u16* __restrict__ NORMED) {
    const int bid = blockIdx.x;
    const int tid = threadIdx.x;

    if (bid < 14848) {      // ---- transpose segments ----
        const float* in; u16* out; int R, C, gx; int t = bid;
        if (t < 1024)              { in = wq; out = QKVT;                         R = 1024; C = 1024; gx = 32; }
        else if ((t -= 1024) < 256)  { in = wk; out = QKVT + (size_t)1024 * 1024; R = 1024; C = 256;  gx = 8; }
        else if ((t -= 256) < 256)   { in = wv; out = QKVT + (size_t)1280 * 1024; R = 1024; C = 256;  gx = 8; }
        else if ((t -= 256) < 1024)  { in = wo; out = WOT;                        R = 1024; C = 1024; gx = 32; }
        else if ((t -= 1024) < 4096) { in = wg; out = WGT;                        R = 1024; C = 4096; gx = 128; }
        else if ((t -= 4096) < 4096) { in = wu; out = WUT;                        R = 1024; C = 4096; gx = 128; }
        else          { t -= 4096;     in = wd; out = WDT;                        R = 4096; C = 1024; gx = 32; }
        const int bx = t % gx, by = t / gx;
        __shared__ float tile[32][33];
        const int c0 = bx * 32, r0 = by * 32;
        const int tx = tid & 31, ty = tid >> 5;
#pragma unroll
        for (int i = ty; i < 32; i += 8)
            tile[i][tx] = in[(size_t)(r0 + i) * C + c0 + tx];
        __syncthreads();
#pragma unroll
        for (int i = ty; i < 32; i += 8)
            out[(size_t)(c0 + i) * R + r0 + tx] = f2bf(tile[tx][i]);
    } else {                // ---- LayerNorm segment ----
        const int row = bid - 14848;
        float4 v = ((const float4*)(x + (size_t)row * 1024))[tid];
        float s = v.x + v.y + v.z + v.w;
        float s2 = v.x * v.x + v.y * v.y + v.z * v.z + v.w * v.w;
#pragma unroll
        for (int off = 1; off < 64; off <<= 1) {
            s += __shfl_xor(s, off);
            s2 += __shfl_xor(s2, off);
        }
        __shared__ float rs[4], rs2[4];
        const int wv4i = tid >> 6;
        if ((tid & 63) == 0) { rs[wv4i] = s; rs2[wv4i] = s2; }
        __syncthreads();
        s = rs[0] + rs[1] + rs[2] + rs[3];
        s2 = rs2[0] + rs2[1] + rs2[2] + rs2[3];
        float mu = s * (1.0f / 1024.0f);
        float var = s2 * (1.0f / 1024.0f) - mu * mu;
        float inv = rsqrtf(var + 1e-5f);
        float4 wv4 = ((const float4*)ln_w)[tid];
        float4 bv4 = ((const float4*)ln_b)[tid];
        ushort4 o;
        o.x = f2bf((v.x - mu) * inv * wv4.x + bv4.x);
        o.y = f2bf((v.y - mu) * inv * wv4.y + bv4.y);
        o.z = f2bf((v.z - mu) * inv * wv4.z + bv4.z);
        o.w = f2bf((v.w - mu) * inv * wv4.w + bv4.w);
        *(ushort4*)(NORMED + (size_t)row * 1024 + tid * 4) = o;
    }
}

// bf16 transpose of V section of qkv: in [B*2048][1536] cols 1280.. -> vT [b][kh][64][2048]
__global__ __launch_bounds__(256) void transpose_v(const u16* __restrict__ in, u16* __restrict__ out,
                                                   int in_stride) {
    __shared__ u16 tile[32][33];
    int b = blockIdx.z;
    int c0 = blockIdx.x * 32, s0 = blockIdx.y * 32;
    int tx = threadIdx.x & 31, ty = threadIdx.x >> 5;
#pragma unroll
    for (int i = ty; i < 32; i += 8)
        tile[i][tx] = in[(size_t)(b * 2048 + s0 + i) * in_stride + c0 + tx];
    __syncthreads();
#pragma unroll
    for (int i = ty; i < 32; i += 8)
        out[(size_t)b * 256 * 2048 + (size_t)(c0 + i) * 2048 + s0 + tx] = tile[tx][i];
}

// ---------------------------------------------------------------- GEMM  C = A[M][K] x Bt[N][K]^T
// BM=128 x BN=64, BK=64, XOR-swizzled LDS (round-7 verified: 0 bank conflicts).
// mode 0: C bf16; mode 1: C f32
__global__ __launch_bounds__(256) void gemm_bt64(const u16* __restrict__ A, const u16* __restrict__ Bt,
                                                 void* __restrict__ Cv,
                                                 int N, int K, int mode) {
    __shared__ __align__(16) u16 As[128 * 64];
    __shared__ __align__(16) u16 Bs[64 * 64];
    const int tid = threadIdx.x, lane = tid & 63, wv = tid >> 6;
    const int row0 = blockIdx.x * 128, col0 = blockIdx.y * 64;
    const int wr = (wv >> 1) * 64, wc = (wv & 1) * 32;
    const int fr = lane & 15, fg = lane >> 4;
    const int lr8 = lane >> 3;
    const int lc8s = ((lane & 7) ^ lr8) * 8;   // pre-swizzled source colblock

    f32x4 acc[4][2];
#pragma unroll
    for (int i = 0; i < 4; ++i)
#pragma unroll
        for (int j = 0; j < 2; ++j) acc[i][j] = (f32x4){0.f, 0.f, 0.f, 0.f};

    const u16* ga = A + (size_t)(row0 + 32 * wv + lr8) * K + lc8s;
    const u16* gb = Bt + (size_t)(col0 + 16 * wv + lr8) * K + lc8s;
    u16* la = As + wv * 2048;
    u16* lb = Bs + wv * 1024;
    const int f7 = fr & 7;

    for (int k0 = 0; k0 < K; k0 += 64) {
        __syncthreads();
        GLLDS(ga + k0, la);
        GLLDS(ga + (size_t)8 * K + k0, la + 512);
        GLLDS(ga + (size_t)16 * K + k0, la + 1024);
        GLLDS(ga + (size_t)24 * K + k0, la + 1536);
        GLLDS(gb + k0, lb);
        GLLDS(gb + (size_t)8 * K + k0, lb + 512);
        __syncthreads();
#pragma unroll
        for (int kk = 0; kk < 2; ++kk) {
            bf16x8 af[4], bfr[2];
#pragma unroll
            for (int i = 0; i < 4; ++i)
                af[i] = *(const bf16x8*)(As + (wr + i * 16 + fr) * 64 + (((kk * 4 + fg) ^ f7) * 8));
#pragma unroll
            for (int j = 0; j < 2; ++j)
                bfr[j] = *(const bf16x8*)(Bs + (wc + j * 16 + fr) * 64 + (((kk * 4 + fg) ^ f7) * 8));
#pragma unroll
            for (int i = 0; i < 4; ++i)
#pragma unroll
                for (int j = 0; j < 2; ++j)
                    acc[i][j] = MFMA16(af[i], bfr[j], acc[i][j]);
        }
    }

    if (mode == 0) {
        u16* C = (u16*)Cv;
#pragma unroll
        for (int i = 0; i < 4; ++i)
#pragma unroll
            for (int j = 0; j < 2; ++j)
#pragma unroll
                for (int r = 0; r < 4; ++r) {
                    int row = row0 + wr + i * 16 + fg * 4 + r;
                    int col = col0 + wc + j * 16 + fr;
                    C[(size_t)row * N + col] = f2bf(acc[i][j][r]);
                }
    } else {
        float* C = (float*)Cv;
#pragma unroll
        for (int i = 0; i < 4; ++i)
#pragma unroll
            for (int j = 0; j < 2; ++j)
#pragma unroll
                for (int r = 0; r < 4; ++r) {
                    int row = row0 + wr + i * 16 + fg * 4 + r;
                    int col = col0 + wc + j * 16 + fr;
                    C[(size_t)row * N + col] = acc[i][j][r];
                }
    }
}

// ---------------------------------------------------------------- fused output GEMM
// out[4096][1024] = x + ATTN @ WOT^T + Hb @ WDT^T  (concatenated K = 5120)
__global__ __launch_bounds__(256) void gemm_out_fused(const u16* __restrict__ A1,
                                                      const u16* __restrict__ B1t,
                                                      const u16* __restrict__ A2,
                                                      const u16* __restrict__ B2t,
                                                      const float* __restrict__ xres,
                                                      float* __restrict__ C) {
    __shared__ __align__(16) u16 As[128 * 64];
    __shared__ __align__(16) u16 Bs[64 * 64];
    const int tid = threadIdx.x, lane = tid & 63, wv = tid >> 6;
    const int row0 = blockIdx.x * 128, col0 = blockIdx.y * 64;
    const int wr = (wv >> 1) * 64, wc = (wv & 1) * 32;
    const int fr = lane & 15, fg = lane >> 4;
    const int lr8 = lane >> 3;
    const int lc8s = ((lane & 7) ^ lr8) * 8;
    const int f7 = fr & 7;

    f32x4 acc[4][2];
#pragma unroll
    for (int i = 0; i < 4; ++i)
#pragma unroll
        for (int j = 0; j < 2; ++j) acc[i][j] = (f32x4){0.f, 0.f, 0.f, 0.f};

    const int rowA = row0 + 32 * wv + lr8;
    const int rowB = col0 + 16 * wv + lr8;
    u16* la = As + wv * 2048;
    u16* lb = Bs + wv * 1024;

    for (int t = 0; t < 80; ++t) {
        const u16* ga;
        const u16* gb;
        size_t sa, sb;
        if (t < 16) {          // segment 1: ATTN @ WOT (K=1024)
            const int ko = t * 64;
            ga = A1 + (size_t)rowA * 1024 + ko + lc8s; sa = 1024;
            gb = B1t + (size_t)rowB * 1024 + ko + lc8s; sb = 1024;
        } else {               // segment 2: Hb @ WDT (K=4096)
            const int ko = (t - 16) * 64;
            ga = A2 + (size_t)rowA * 4096 + ko + lc8s; sa = 4096;
            gb = B2t + (size_t)rowB * 4096 + ko + lc8s; sb = 4096;
        }
        __syncthreads();
        GLLDS(ga, la);
        GLLDS(ga + 8 * sa, la + 512);
        GLLDS(ga + 16 * sa, la + 1024);
        GLLDS(ga + 24 * sa, la + 1536);
        GLLDS(gb, lb);
        GLLDS(gb + 8 * sb, lb + 512);
        __syncthreads();
#pragma unroll
        for (int kk = 0; kk < 2; ++kk) {
            bf16x8 af[4], bfr[2];
#pragma unroll
            for (int i = 0; i < 4; ++i)
                af[i] = *(const bf16x8*)(As + (wr + i * 16 + fr) * 64 + (((kk * 4 + fg) ^ f7) * 8));
#pragma unroll
            for (int j = 0; j < 2; ++j)
                bfr[j] = *(const bf16x8*)(Bs + (wc + j * 16 + fr) * 64 + (((kk * 4 + fg) ^ f7) * 8));
#pragma unroll
            for (int i = 0; i < 4; ++i)
#pragma unroll
                for (int j = 0; j < 2; ++j)
                    acc[i][j] = MFMA16(af[i], bfr[j], acc[i][j]);
        }
    }

#pragma unroll
    for (int i = 0; i < 4; ++i)
#pragma unroll
        for (int j = 0; j < 2; ++j)
#pragma unroll
            for (int r = 0; r < 4; ++r) {
                int row = row0 + wr + i * 16 + fg * 4 + r;
                int col = col0 + wc + j * 16 + fr;
                size_t off = (size_t)row * 1024 + col;
                C[off] = acc[i][j][r] + xres[off];
            }
}

// ---------------------------------------------------------------- fused gate+up GEMM
// H = silu(A x Bg^T) * (A x Bu^T), all bf16. BM=128 x BN=64, BK=64, swizzled LDS.
// (round-7 verified: 89 us, MfmaUtil 32-33%, 0 bank conflicts.)
__global__ __launch_bounds__(256) void gemm_gateup(const u16* __restrict__ A,
                                                   const u16* __restrict__ Bg,
                                                   const u16* __restrict__ Bu,
                                                   u16* __restrict__ H, int N, int K) {
    __shared__ __align__(16) u16 As[128 * 64];
    __shared__ __align__(16) u16 Bgs[64 * 64];
    __shared__ __align__(16) u16 Bus[64 * 64];
    const int tid = threadIdx.x, lane = tid & 63, wv = tid >> 6;
    const int row0 = blockIdx.x * 128, col0 = blockIdx.y * 64;
    const int wr = (wv >> 1) * 64, wc = (wv & 1) * 32;
    const int fr = lane & 15, fg = lane >> 4;
    const int lr8 = lane >> 3;
    const int lc8s = ((lane & 7) ^ lr8) * 8;

    f32x4 ag[4][2], au[4][2];
#pragma unroll
    for (int i = 0; i < 4; ++i)
#pragma unroll
        for (int j = 0; j < 2; ++j) {
            ag[i][j] = (f32x4){0.f, 0.f, 0.f, 0.f};
            au[i][j] = (f32x4){0.f, 0.f, 0.f, 0.f};
        }

    const u16* ga = A + (size_t)(row0 + 32 * wv + lr8) * K + lc8s;
    const u16* gg = Bg + (size_t)(col0 + 16 * wv + lr8) * K + lc8s;
    const u16* gu = Bu + (size_t)(col0 + 16 * wv + lr8) * K + lc8s;
    u16* la = As + wv * 2048;
    u16* lg = Bgs + wv * 1024;
    u16* lu = Bus + wv * 1024;
    const int f7 = fr & 7;

    for (int k0 = 0; k0 < K; k0 += 64) {
        __syncthreads();
        GLLDS(ga + k0, la);
        GLLDS(ga + (size_t)8 * K + k0, la + 512);
        GLLDS(ga + (size_t)16 * K + k0, la + 1024);
        GLLDS(ga + (size_t)24 * K + k0, la + 1536);
        GLLDS(gg + k0, lg);
        GLLDS(gg + (size_t)8 * K + k0, lg + 512);
        GLLDS(gu + k0, lu);
        GLLDS(gu + (size_t)8 * K + k0, lu + 512);
        __syncthreads();
#pragma unroll
        for (int kk = 0; kk < 2; ++kk) {
            bf16x8 af[4], bg[2], bu[2];
#pragma unroll
            for (int i = 0; i < 4; ++i)
                af[i] = *(const bf16x8*)(As + (wr + i * 16 + fr) * 64 + (((kk * 4 + fg) ^ f7) * 8));
#pragma unroll
            for (int j = 0; j < 2; ++j) {
                bg[j] = *(const bf16x8*)(Bgs + (wc + j * 16 + fr) * 64 + (((kk * 4 + fg) ^ f7) * 8));
                bu[j] = *(const bf16x8*)(Bus + (wc + j * 16 + fr) * 64 + (((kk * 4 + fg) ^ f7) * 8));
            }
#pragma unroll
            for (int i = 0; i < 4; ++i)
#pragma unroll
                for (int j = 0; j < 2; ++j) {
                    ag[i][j] = MFMA16(af[i], bg[j], ag[i][j]);
                    au[i][j] = MFMA16(af[i], bu[j], au[i][j]);
                }
        }
    }

#pragma unroll
    for (int i = 0; i < 4; ++i)
#pragma unroll
        for (int j = 0; j < 2; ++j)
#pragma unroll
            for (int r = 0; r < 4; ++r) {
                int row = row0 + wr + i * 16 + fg * 4 + r;
                int col = col0 + wc + j * 16 + fr;
                float g = ag[i][j][r];
                float sg = g / (1.0f + __expf(-g));
                H[(size_t)row * N + col] = f2bf(sg * au[i][j][r]);
            }
}

// ---------------------------------------------------------------- flash attention, 8-warp 32x32
__global__ __launch_bounds__(512) void attn_kernel(const u16* __restrict__ qkv,
                                                   const u16* __restrict__ Vt,
                                                   u16* __restrict__ Ob) {
    __shared__ __align__(16) u16 Ks[2][64 * 64];
    __shared__ __align__(16) u16 Vs[2][64 * 64];
    const int tid = threadIdx.x, lane = tid & 63, w = tid >> 6;
    const int bid = blockIdx.x;
    const int qblk = 7 - (bid & 7);      // longest blocks dispatch first
    const int h = (bid >> 3) & 15;
    const int b = bid >> 7;
    const int kh = h >> 2;
    const int q0 = qblk * 256;
    const int lo = lane & 31, hi = lane >> 5;
    const int qg = q0 + w * 32 + lo;
    const int S = 2048, QS = 1536;

    bf16x8 qf[4];
    {
        const u16* qrow = qkv + (size_t)(b * S + qg) * QS + h * 64 + 8 * hi;
        qf[0] = *(const bf16x8*)(qrow);
        qf[1] = *(const bf16x8*)(qrow + 16);
        qf[2] = *(const bf16x8*)(qrow + 32);
        qf[3] = *(const bf16x8*)(qrow + 48);
    }

    f32x16 o0 = {}, o1 = {};
    float mr = -1e30f, ls = 0.f;
    const int nt = (q0 >> 6) + 4;
    const int wq0 = q0 + w * 32;

    const int sr = w * 8 + (lane >> 3);
    const int scb = ((lane & 7) ^ (sr & 7)) * 8;
    const u16* kg = qkv + (size_t)b * S * QS + 1024 + kh * 64 + scb;
    const u16* vg = Vt + (size_t)(b * 4 + kh) * 64 * 2048 + (size_t)sr * 2048 + scb;
    u16* lk = (u16*)Ks + w * 512;
    u16* lv = (u16*)Vs + w * 512;

#define STAGE(buf, t) { const int kv0s = (t) * 64; \
    GLLDS(kg + (size_t)(kv0s + sr) * QS, lk + (buf) * 4096); \
    GLLDS(vg + kv0s, lv + (buf) * 4096); }

    STAGE(0, 0)
    asm volatile("s_waitcnt vmcnt(0)" ::: "memory");
    __syncthreads();

    const int lrow = lo * 64;
    const int l7 = lo & 7;

    for (int t = 0; t < nt; ++t) {
        const int cur = t & 1;
        if (t + 1 < nt) STAGE(cur ^ 1, t + 1)
        const int kv0 = t * 64;
        if (kv0 <= wq0 + 31) {
            const u16* KB = (const u16*)Ks + cur * 4096;
            const u16* VB = (const u16*)Vs + cur * 4096;
            f32x16 sc0 = {}, sc1 = {};
#pragma unroll
            for (int ds = 0; ds < 4; ++ds) {
                bf16x8 kf0 = *(const bf16x8*)(KB + lrow + (((2 * ds + hi) ^ l7) * 8));
                sc0 = MFMA32(kf0, qf[ds], sc0);
                bf16x8 kf1 = *(const bf16x8*)(KB + 2048 + lrow + (((2 * ds + hi) ^ l7) * 8));
                sc1 = MFMA32(kf1, qf[ds], sc1);
            }

            float xv[32];
            if (kv0 + 63 <= wq0) {
#pragma unroll
                for (int i = 0; i < 16; ++i) {
                    xv[i] = sc0[i] * 0.125f;
                    xv[16 + i] = sc1[i] * 0.125f;
                }
            } else {
#pragma unroll
                for (int i = 0; i < 16; ++i) {
                    int k0g = kv0 + (i & 3) + 8 * (i >> 2) + 4 * hi;
                    xv[i]      = (k0g      <= qg) ? sc0[i] * 0.125f : -1e30f;
                    xv[16 + i] = (k0g + 32 <= qg) ? sc1[i] * 0.125f : -1e30f;
                }
            }
            float m = xv[0];
#pragma unroll
            for (int i = 1; i < 32; ++i) m = fmaxf(m, xv[i]);
            m = fmaxf(m, __shfl_xor(m, 32));
            float nm = fmaxf(mr, m);
            float al = __expf(mr - nm);
            mr = nm;
            float sum = 0.f;
#pragma unroll
            for (int i = 0; i < 32; ++i) {
                float p = __expf(xv[i] - nm);
                xv[i] = p;
                sum += p;
            }
            sum += __shfl_xor(sum, 32);
            ls = ls * al + sum;
#pragma unroll
            for (int i = 0; i < 16; ++i) { o0[i] *= al; o1[i] *= al; }

            bf16x8 pf[4];
#pragma unroll
            for (int g = 0; g < 4; ++g) {
                uint32_t w0, w1, w2, w3;
                asm("v_cvt_pk_bf16_f32 %0, %1, %2" : "=v"(w0) : "v"(xv[g * 8 + 0]), "v"(xv[g * 8 + 1]));
                asm("v_cvt_pk_bf16_f32 %0, %1, %2" : "=v"(w1) : "v"(xv[g * 8 + 2]), "v"(xv[g * 8 + 3]));
                asm("v_cvt_pk_bf16_f32 %0, %1, %2" : "=v"(w2) : "v"(xv[g * 8 + 4]), "v"(xv[g * 8 + 5]));
                asm("v_cvt_pk_bf16_f32 %0, %1, %2" : "=v"(w3) : "v"(xv[g * 8 + 6]), "v"(xv[g * 8 + 7]));
                asm volatile("v_permlane32_swap_b32 %0, %1" : "+v"(w0), "+v"(w2));
                asm volatile("v_permlane32_swap_b32 %0, %1" : "+v"(w1), "+v"(w3));
                union { uint32_t u[4]; bf16x8 v; } pk;
                pk.u[0] = w0; pk.u[1] = w1; pk.u[2] = w2; pk.u[3] = w3;
                pf[g] = pk.v;
            }

#pragma unroll
            for (int ks = 0; ks < 4; ++ks) {
                bf16x8 vf0 = *(const bf16x8*)(VB + lrow + (((2 * ks + hi) ^ l7) * 8));
                o0 = MFMA32(vf0, pf[ks], o0);
                bf16x8 vf1 = *(const bf16x8*)(VB + 2048 + lrow + (((2 * ks + hi) ^ l7) * 8));
                o1 = MFMA32(vf1, pf[ks], o1);
            }
        }
        asm volatile("s_waitcnt vmcnt(0)" ::: "memory");
        __syncthreads();
    }
#undef STAGE

    const float inv = 1.0f / ls;
    u16* orow = Ob + (size_t)(b * S + qg) * 1024 + h * 64;
#pragma unroll
    for (int rg = 0; rg < 4; ++rg) {
        ushort4 w4;
        w4.x = f2bf(o0[rg * 4 + 0] * inv);
        w4.y = f2bf(o0[rg * 4 + 1] * inv);
        w4.z = f2bf(o0[rg * 4 + 2] * inv);
        w4.w = f2bf(o0[rg * 4 + 3] * inv);
        *(ushort4*)(orow + rg * 8 + 4 * hi) = w4;
        w4.x = f2bf(o1[rg * 4 + 0] * inv);
        w4.y = f2bf(o1[rg * 4 + 1] * inv);
        w4.z = f2bf(o1[rg * 4 + 2] * inv);
        w4.w = f2bf(o1[rg * 4 + 3] * inv);
        *(ushort4*)(orow + 32 + rg * 8 + 4 * hi) = w4;
    }
}

// ---------------------------------------------------------------- launch
extern "C" void kernel_launch(void* const* d_in, const int* in_sizes, int n_in,
                              void* d_out, int out_size, void* d_ws, size_t ws_size,
                              hipStream_t stream) {
    const float* x    = (const float*)d_in[0];
    const float* ln_w = (const float*)d_in[1];
    const float* ln_b = (const float*)d_in[2];
    const float* wq   = (const float*)d_in[3];
    const float* wk   = (const float*)d_in[4];
    const float* wv   = (const float*)d_in[5];
    const float* wo   = (const float*)d_in[6];
    const float* wg   = (const float*)d_in[7];
    const float* wu   = (const float*)d_in[8];
    const float* wd   = (const float*)d_in[9];
    float* out = (float*)d_out;

    char* ws = (char*)d_ws;
    u16* QKVT   = (u16*)(ws + 0x0000000);   // [1536][1024] bf16  3MB
    u16* WOT    = (u16*)(ws + 0x0300000);   // [1024][1024] bf16  2MB
    u16* WGT    = (u16*)(ws + 0x0500000);   // [4096][1024] bf16  8MB
    u16* WUT    = (u16*)(ws + 0x0D00000);   // [4096][1024] bf16  8MB
    u16* WDT    = (u16*)(ws + 0x1500000);   // [1024][4096] bf16  8MB
    u16* NORMED = (u16*)(ws + 0x1D00000);   // [4096][1024] bf16  8MB
    u16* QKV    = (u16*)(ws + 0x2500000);   // [4096][1536] bf16 12MB
    u16* VT     = (u16*)(ws + 0x3100000);   // [2][4][64][2048]   2MB
    u16* ATTN   = (u16*)(ws + 0x3300000);   // [4096][1024] bf16  8MB
    u16* Hb     = (u16*)(ws + 0x3B00000);   // [4096][4096] bf16 32MB

    // 1. fused preprocessing: all weight transposes + layernorm (one launch)
    prep_kernel<<<18944, 256, 0, stream>>>(wq, wk, wv, wo, wg, wu, wd,
                                           x, ln_w, ln_b,
                                           QKVT, WOT, WGT, WUT, WDT, NORMED);

    // 2. attention path
    gemm_bt64<<<dim3(32, 24), 256, 0, stream>>>(NORMED, QKVT, QKV, 1536, 1024, 0);
    transpose_v<<<dim3(8, 64, 2), 256, 0, stream>>>(QKV + 1280, VT, 1536);
    attn_kernel<<<256, 512, 0, stream>>>(QKV, VT, ATTN);

    // 3. FFN gate+up (2-phase, round-7 structure)
    gemm_gateup<<<dim3(32, 64), 256, 0, stream>>>(NORMED, WGT, WUT, Hb, 4096, 1024);

    // 4. fused output: out = x + ATTN@WO^T + Hb@WD^T  (K=5120 concatenated)
    gemm_out_fused<<<dim3(32, 16), 256, 0, stream>>>(ATTN, WOT, Hb, WDT, x, out);
}